// Round 6
// baseline (1714.672 us; speedup 1.0000x reference)
//
#include <hip/hip_runtime.h>
#include <math.h>

#define TT 8
#define NN 4096
#define FF 128

// bf16 MFMA fragments as short8 (guide-verified compile form on gfx950)
typedef short bf16x8 __attribute__((ext_vector_type(8)));
typedef float f32x4 __attribute__((ext_vector_type(4)));

__device__ inline ushort f2bf(float f) {              // RNE fp32 -> bf16 bits
  uint u = __float_as_uint(f);
  return (ushort)((u + 0x7fffu + ((u >> 16) & 1u)) >> 16);
}
__device__ inline float bf2f(ushort h) { return __uint_as_float(((uint)h) << 16); }

__device__ inline void split8(const float* v, uint4& H, uint4& L) {
  ushort h[8], l[8];
  #pragma unroll
  for (int j = 0; j < 8; ++j) {
    h[j] = f2bf(v[j]);
    l[j] = f2bf(v[j] - bf2f(h[j]));
  }
  H = make_uint4((uint)h[0] | ((uint)h[1] << 16), (uint)h[2] | ((uint)h[3] << 16),
                 (uint)h[4] | ((uint)h[5] << 16), (uint)h[6] | ((uint)h[7] << 16));
  L = make_uint4((uint)l[0] | ((uint)l[1] << 16), (uint)l[2] | ((uint)l[3] << 16),
                 (uint)l[4] | ((uint)l[5] << 16), (uint)l[6] | ((uint)l[7] << 16));
}

// ---------------------------------------------------------------------------
// p normalization: pn = p / ||p||
// ---------------------------------------------------------------------------
__global__ void norm_p_k(const float* __restrict__ p1, const float* __restrict__ p2,
                         float* __restrict__ pn1, float* __restrict__ pn2) {
  int b = blockIdx.x;
  int which = b >> 3, t = b & 7;
  const float* src = which ? p2 : p1;
  float* dst = which ? pn2 : pn1;
  int lane = threadIdx.x;
  float v0 = src[t*FF + lane];
  float v1 = src[t*FF + 64 + lane];
  float ss = v0*v0 + v1*v1;
  #pragma unroll
  for (int o = 32; o > 0; o >>= 1) ss += __shfl_xor(ss, o);
  float inv = 1.0f / sqrtf(ss);
  dst[t*FF + lane] = v0 * inv;
  dst[t*FF + 64 + lane] = v1 * inv;
}

// ---------------------------------------------------------------------------
// scores[t][n] = dot(src[t][n][:], pn[t][:])
// ---------------------------------------------------------------------------
__global__ __launch_bounds__(256)
void scores_k(const float* __restrict__ src, const float* __restrict__ pn,
              float* __restrict__ sc) {
  __shared__ float ps[FF];
  int t = blockIdx.y;
  int tid = threadIdx.x;
  if (tid < FF) ps[tid] = pn[t*FF + tid];
  __syncthreads();
  int row = blockIdx.x * 64 + (tid >> 2);
  int part = tid & 3;
  const float* rp = src + ((long)t*NN + row)*FF + part*32;
  float acc = 0.f;
  #pragma unroll
  for (int i = 0; i < 8; ++i) {
    float4 f = *reinterpret_cast<const float4*>(rp + i*4);
    const float* pp = ps + part*32 + i*4;
    acc += f.x*pp[0] + f.y*pp[1] + f.z*pp[2] + f.w*pp[3];
  }
  acc += __shfl_xor(acc, 1);
  acc += __shfl_xor(acc, 2);
  if (part == 0) sc[t*NN + row] = acc;
}

// ---------------------------------------------------------------------------
// Full bitonic sort (desc score, tie -> lower index), then
// z[t][r][c] = src[t][idx[c]][r] * tanh(vals[c]).  One block per t.
// ---------------------------------------------------------------------------
template<int K>
__global__ __launch_bounds__(1024)
void sortz_k(const float* __restrict__ sc, const float* __restrict__ src,
             float* __restrict__ z) {
  __shared__ float s[NN];
  __shared__ int  si[NN];
  __shared__ float tv[K];
  int t = blockIdx.x, tid = threadIdx.x;
  for (int i = tid; i < NN; i += 1024) { s[i] = sc[(long)t*NN + i]; si[i] = i; }
  __syncthreads();
  for (int k = 2; k <= NN; k <<= 1) {
    for (int j = k >> 1; j > 0; j >>= 1) {
      for (int i = tid; i < NN; i += 1024) {
        int l = i ^ j;
        if (l > i) {
          float a = s[i], b = s[l]; int ia = si[i], ib = si[l];
          bool dir = ((i & k) == 0);
          bool lp = (b > a) || (b == a && ib < ia);
          if (lp == dir) { s[i] = b; s[l] = a; si[i] = ib; si[l] = ia; }
        }
      }
      __syncthreads();
    }
  }
  if (tid < K) tv[tid] = tanhf(s[tid]);
  __syncthreads();
  for (int e = tid; e < FF*K; e += 1024) {
    int c = e >> 7, r = e & 127;
    z[((long)t*FF + r)*K + c] = src[((long)t*NN + si[c])*FF + r] * tv[c];
  }
}

// ---------------------------------------------------------------------------
// GRU cell (sequential over t).
// ---------------------------------------------------------------------------
template<int C>
__global__ __launch_bounds__(128)
void cell_k(const float* __restrict__ W, const float* __restrict__ U,
            const float* __restrict__ B, const float* __restrict__ z,
            const float* __restrict__ Qp, float* __restrict__ Qo) {
  __shared__ float zc[4][FF], qc[4][FF], rq[4][FF];
  int i = threadIdx.x;
  int j0 = blockIdx.x * 4;
  #pragma unroll
  for (int jj = 0; jj < 4; ++jj) {
    zc[jj][i] = z[i*C + j0 + jj];
    qc[jj][i] = Qp[i*C + j0 + jj];
  }
  __syncthreads();
  float a0[4] = {0,0,0,0}, a1[4] = {0,0,0,0};
  const float* W0 = W + i*FF;            const float* W1r = W + FF*FF + i*FF;
  const float* U0 = U + i*FF;            const float* U1r = U + FF*FF + i*FF;
  #pragma unroll 4
  for (int k = 0; k < FF; ++k) {
    float w0 = W0[k], w1 = W1r[k], u0 = U0[k], u1 = U1r[k];
    #pragma unroll
    for (int jj = 0; jj < 4; ++jj) {
      a0[jj] += w0*zc[jj][k] + u0*qc[jj][k];
      a1[jj] += w1*zc[jj][k] + u1*qc[jj][k];
    }
  }
  float uu[4];
  #pragma unroll
  for (int jj = 0; jj < 4; ++jj) {
    float xu = a0[jj] + B[0*FF*C + i*C + j0+jj];
    uu[jj] = 1.0f / (1.0f + expf(-xu));
    float xr = a1[jj] + B[1*FF*C + i*C + j0+jj];
    float r = 1.0f / (1.0f + expf(-xr));
    rq[jj][i] = r * qc[jj][i];
  }
  __syncthreads();
  float ah[4] = {0,0,0,0};
  const float* W2 = W + 2*FF*FF + i*FF;  const float* U2 = U + 2*FF*FF + i*FF;
  #pragma unroll 4
  for (int k = 0; k < FF; ++k) {
    float w2 = W2[k], u2 = U2[k];
    #pragma unroll
    for (int jj = 0; jj < 4; ++jj) ah[jj] += w2*zc[jj][k] + u2*rq[jj][k];
  }
  #pragma unroll
  for (int jj = 0; jj < 4; ++jj) {
    float h = tanhf(ah[jj] + B[2*FF*C + i*C + j0+jj]);
    float q = qc[jj][i];
    Qo[i*C + j0+jj] = (1.0f - uu[jj])*q + uu[jj]*h;
  }
}

// ---------------------------------------------------------------------------
// Layer-1 X: X1 = feats[t] @ Q1[t], written DIRECTLY as split-bf16 in MFMA
// B-fragment order: Bp[t][k>>3][c][k&7] (hi and lo). grid (128, 8), 256 thr.
// ---------------------------------------------------------------------------
__global__ __launch_bounds__(256)
void xmul_pack_k(const float* __restrict__ in, const float* __restrict__ Q,
                 ushort* __restrict__ Bph, ushort* __restrict__ Bpl) {
  constexpr int C = 128, RPT = 16;
  __shared__ float Qs[64*C];
  __shared__ float ft[FF][36];
  int t = blockIdx.y;
  const float* inT = in + (long)t*NN*FF;
  const float* QT  = Q  + (long)t*128*128;
  int tid = threadIdx.x;
  int r0 = blockIdx.x * 32;
  for (int v = tid; v < 32*FF/4; v += 256) {
    int row = v >> 5, kq = v & 31;
    float4 f = *reinterpret_cast<const float4*>(inT + ((long)(r0+row))*FF + kq*4);
    ft[kq*4+0][row] = f.x; ft[kq*4+1][row] = f.y;
    ft[kq*4+2][row] = f.z; ft[kq*4+3][row] = f.w;
  }
  int c = tid & (C-1);
  int rh = tid / C;
  float acc[RPT];
  #pragma unroll
  for (int r = 0; r < RPT; ++r) acc[r] = 0.f;
  for (int kc = 0; kc < 2; ++kc) {
    __syncthreads();
    for (int v = tid*4; v < 64*C; v += 1024)
      *reinterpret_cast<float4*>(&Qs[v]) =
        *reinterpret_cast<const float4*>(QT + kc*64*C + v);
    __syncthreads();
    #pragma unroll 8
    for (int kl = 0; kl < 64; ++kl) {
      int k = kc*64 + kl;
      float qv = Qs[kl*C + c];
      const float* fr = &ft[k][rh*RPT];
      #pragma unroll
      for (int r4 = 0; r4 < RPT/4; ++r4) {
        float4 fv = *reinterpret_cast<const float4*>(fr + r4*4);
        acc[r4*4+0] += fv.x*qv; acc[r4*4+1] += fv.y*qv;
        acc[r4*4+2] += fv.z*qv; acc[r4*4+3] += fv.w*qv;
      }
    }
  }
  // pack: rows k0..k0+7 (aligned 8-groups), col c -> 16B hi + 16B lo per group
  #pragma unroll
  for (int g = 0; g < 2; ++g) {
    uint4 H, L;
    split8(&acc[g*8], H, L);
    long k0 = r0 + rh*16 + g*8;
    long off = ((long)t*512*128 + (k0 >> 3)*128 + c)*8;
    *reinterpret_cast<uint4*>(&Bph[off]) = H;
    *reinterpret_cast<uint4*>(&Bpl[off]) = L;
  }
}

// ---------------------------------------------------------------------------
// Layer-2 X: Y = h1[7] @ Q2[7], fp32 out (feeds fp32 final GEMM).
// ---------------------------------------------------------------------------
__global__ __launch_bounds__(256)
void xmul_k64(const float* __restrict__ in, const float* __restrict__ Q,
              float* __restrict__ out) {
  constexpr int C = 64, RPT = 8;
  __shared__ float Qs[64*C];
  __shared__ float ft[FF][36];
  const float* inT = in;
  const float* QT  = Q;
  int tid = threadIdx.x;
  int r0 = blockIdx.x * 32;
  for (int v = tid; v < 32*FF/4; v += 256) {
    int row = v >> 5, kq = v & 31;
    float4 f = *reinterpret_cast<const float4*>(inT + ((long)(r0+row))*FF + kq*4);
    ft[kq*4+0][row] = f.x; ft[kq*4+1][row] = f.y;
    ft[kq*4+2][row] = f.z; ft[kq*4+3][row] = f.w;
  }
  int c = tid & (C-1);
  int rh = tid / C;
  float acc[RPT];
  #pragma unroll
  for (int r = 0; r < RPT; ++r) acc[r] = 0.f;
  for (int kc = 0; kc < 2; ++kc) {
    __syncthreads();
    for (int v = tid*4; v < 64*C; v += 1024)
      *reinterpret_cast<float4*>(&Qs[v]) =
        *reinterpret_cast<const float4*>(QT + kc*64*C + v);
    __syncthreads();
    #pragma unroll 8
    for (int kl = 0; kl < 64; ++kl) {
      int k = kc*64 + kl;
      float qv = Qs[kl*C + c];
      const float* fr = &ft[k][rh*RPT];
      #pragma unroll
      for (int r4 = 0; r4 < RPT/4; ++r4) {
        float4 fv = *reinterpret_cast<const float4*>(fr + r4*4);
        acc[r4*4+0] += fv.x*qv; acc[r4*4+1] += fv.y*qv;
        acc[r4*4+2] += fv.z*qv; acc[r4*4+3] += fv.w*qv;
      }
    }
  }
  #pragma unroll
  for (int r = 0; r < RPT; ++r)
    out[((long)(r0 + rh*RPT + r))*C + c] = acc[r];
}

// ---------------------------------------------------------------------------
// Layer-1 big GEMM via split-bf16 MFMA: h1[t] = relu(adj[t] @ X1[t]).
// BM=64 (4 waves x 16 rows), BN=128 (full), BK=32 (1 MFMA-K per step).
// A: fp32 global -> in-kernel hi/lo split -> double-buffered LDS
//    (row stride 40 ushorts = 80B; write/read patterns are uniform
//    8 words/bank per wave = data-volume minimum, conflict-free).
// B: pre-packed k-major frags read straight from global (L2-resident;
//    t = bid&7 pins one t per XCD so the 2MB panel stays in that L2).
// 3-product split: AhiBhi + AloBhi + AhiBlo (drop AloBlo ~2^-18 rel/term).
// ---------------------------------------------------------------------------
#define ASTRIDE 40

__global__ __launch_bounds__(256, 2)
void gemm_mfma_k(const float* __restrict__ A, const ushort* __restrict__ Bph,
                 const ushort* __restrict__ Bpl, float* __restrict__ H) {
  __shared__ ushort AsH[2][64*ASTRIDE];
  __shared__ ushort AsL[2][64*ASTRIDE];
  int bid = blockIdx.x;
  int t = bid & 7, mb = bid >> 3;
  const float* At = A + (size_t)t*NN*NN + (size_t)mb*64*NN;
  const ushort* BhT = Bph + (size_t)t*512*128*8;
  const ushort* BlT = Bpl + (size_t)t*512*128*8;
  float* Ht = H + (size_t)t*NN*FF + (size_t)mb*64*FF;

  int tid = threadIdx.x;
  int wave = tid >> 6, lane = tid & 63;
  int lg = lane >> 4, lr = lane & 15;

  // A staging: thread -> row tid>>2 (0..63), k-octet tid&3
  int srow = tid >> 2, skq = tid & 3;
  const float* aLoad = At + (size_t)srow*NN + skq*8;
  int sOff = srow*ASTRIDE + skq*8;                 // ushort elems, 16B aligned

  // A-frag read: row 16*wave + lr, k-local lg*8..lg*8+7
  int fOff = (16*wave + lr)*ASTRIDE + lg*8;

  // B-frag base (ushort elems): step s, nsub n -> s*4096 + lg*1024 + lr*8 + n*128
  size_t bOff = (size_t)lg*1024 + (size_t)lr*8;

  f32x4 acc[8];
  #pragma unroll
  for (int n = 0; n < 8; ++n) acc[n] = (f32x4){0.f, 0.f, 0.f, 0.f};

  {
    float4 a0 = *reinterpret_cast<const float4*>(aLoad);
    float4 a1 = *reinterpret_cast<const float4*>(aLoad + 4);
    float v[8] = {a0.x,a0.y,a0.z,a0.w,a1.x,a1.y,a1.z,a1.w};
    uint4 Hh, Ll; split8(v, Hh, Ll);
    *reinterpret_cast<uint4*>(&AsH[0][sOff]) = Hh;
    *reinterpret_cast<uint4*>(&AsL[0][sOff]) = Ll;
  }
  __syncthreads();

  for (int s = 0; s < 128; ++s) {
    int cur = s & 1;
    float4 a0, a1;
    if (s < 127) {                                  // next A chunk in flight
      a0 = *reinterpret_cast<const float4*>(aLoad + (s+1)*32);
      a1 = *reinterpret_cast<const float4*>(aLoad + (s+1)*32 + 4);
    }
    const ushort* bh = BhT + (size_t)s*4096 + bOff;
    const ushort* bl = BlT + (size_t)s*4096 + bOff;
    bf16x8 ah = *reinterpret_cast<const bf16x8*>(&AsH[cur][fOff]);
    bf16x8 al = *reinterpret_cast<const bf16x8*>(&AsL[cur][fOff]);
    #pragma unroll
    for (int n = 0; n < 8; ++n) {
      bf16x8 bhf = *reinterpret_cast<const bf16x8*>(bh + n*128);
      bf16x8 blf = *reinterpret_cast<const bf16x8*>(bl + n*128);
      acc[n] = __builtin_amdgcn_mfma_f32_16x16x32_bf16(ah, bhf, acc[n], 0, 0, 0);
      acc[n] = __builtin_amdgcn_mfma_f32_16x16x32_bf16(al, bhf, acc[n], 0, 0, 0);
      acc[n] = __builtin_amdgcn_mfma_f32_16x16x32_bf16(ah, blf, acc[n], 0, 0, 0);
    }
    if (s < 127) {
      float v[8] = {a0.x,a0.y,a0.z,a0.w,a1.x,a1.y,a1.z,a1.w};
      uint4 Hh, Ll; split8(v, Hh, Ll);
      *reinterpret_cast<uint4*>(&AsH[cur^1][sOff]) = Hh;
      *reinterpret_cast<uint4*>(&AsL[cur^1][sOff]) = Ll;
    }
    __syncthreads();
  }

  // D[row][col]: col = lane&15, row = (lane>>4)*4 + v   [m89-verified]
  #pragma unroll
  for (int n = 0; n < 8; ++n)
    #pragma unroll
    for (int v = 0; v < 4; ++v)
      Ht[(size_t)(16*wave + lg*4 + v)*FF + 16*n + lr] = fmaxf(acc[n][v], 0.f);
}

// ---------------------------------------------------------------------------
// Final fp32 GEMM (layer 2, t=7 only): out = adj[7] @ Y.  Kept fp32 so the
// compared output has no split-bf16 error contribution.
// ---------------------------------------------------------------------------
__global__ __launch_bounds__(256, 2)
void gemm_adj64_k(const float* __restrict__ A, const float* __restrict__ X,
                  float* __restrict__ C_) {
  constexpr int BM = 64, KB = 32, BN = 64, TN = 4, XROW = 72;
  __shared__ float As[KB][BM+4];
  __shared__ float Xs[KB*XROW];
  const float* At = A;
  const float* Xt = X;
  float* Ct = C_;
  int brow = blockIdx.x * BM;
  int tid = threadIdx.x;
  int tr = tid >> 4, tc = tid & 15;
  int arow = tid & 63, aq = tid >> 6;
  int xkk = tid >> 3;
  int xcg = (tid & 7) * 8;

  float acc[4][TN];
  #pragma unroll
  for (int i = 0; i < 4; ++i)
    #pragma unroll
    for (int j = 0; j < TN; ++j) acc[i][j] = 0.f;

  float4 ar0, ar1, xr0, xr1;
  const float* aBase = At + ((long)(brow + arow))*NN;

  auto loadG = [&](int k0) {
    ar0 = *reinterpret_cast<const float4*>(aBase + k0 + aq*8);
    ar1 = *reinterpret_cast<const float4*>(aBase + k0 + aq*8 + 4);
    const float* xp = Xt + ((long)(k0 + xkk))*BN + xcg;
    xr0 = *reinterpret_cast<const float4*>(xp);
    xr1 = *reinterpret_cast<const float4*>(xp + 4);
  };
  auto storeL = [&]() {
    As[aq*8+0][arow] = ar0.x; As[aq*8+1][arow] = ar0.y;
    As[aq*8+2][arow] = ar0.z; As[aq*8+3][arow] = ar0.w;
    As[aq*8+4][arow] = ar1.x; As[aq*8+5][arow] = ar1.y;
    As[aq*8+6][arow] = ar1.z; As[aq*8+7][arow] = ar1.w;
    int base = xkk*XROW + xcg;
    *reinterpret_cast<float4*>(&Xs[base+0]) = xr0;
    *reinterpret_cast<float4*>(&Xs[base+4]) = xr1;
  };
  auto compute = [&]() {
    #pragma unroll 8
    for (int kk = 0; kk < KB; ++kk) {
      float4 av = *reinterpret_cast<const float4*>(&As[kk][tr*4]);
      float4 b0 = *reinterpret_cast<const float4*>(&Xs[kk*XROW + tc*4]);
      float xv[TN] = {b0.x, b0.y, b0.z, b0.w};
      float am[4] = {av.x, av.y, av.z, av.w};
      #pragma unroll
      for (int i = 0; i < 4; ++i)
        #pragma unroll
        for (int j = 0; j < TN; ++j)
          acc[i][j] += am[i]*xv[j];
    }
  };

  loadG(0);
  storeL();
  __syncthreads();
  for (int ch = 1; ch < NN/KB; ++ch) {
    loadG(ch*KB);
    compute();
    __syncthreads();
    storeL();
    __syncthreads();
  }
  compute();

  #pragma unroll
  for (int i = 0; i < 4; ++i) {
    int row = brow + tr*4 + i;
    float* op = Ct + (long)row*BN + tc*TN;
    float4 o;
    o.x = acc[i][0]; o.y = acc[i][1]; o.z = acc[i][2]; o.w = acc[i][3];
    *reinterpret_cast<float4*>(op) = o;
  }
}

// ---------------------------------------------------------------------------
extern "C" void kernel_launch(void* const* d_in, const int* in_sizes, int n_in,
                              void* d_out, int out_size, void* d_ws, size_t ws_size,
                              hipStream_t stream) {
  (void)in_sizes; (void)n_in; (void)out_size; (void)ws_size;
  const float* adj   = (const float*)d_in[0];
  const float* feats = (const float*)d_in[1];
  const float* p1    = (const float*)d_in[2];
  const float* p2    = (const float*)d_in[3];
  const float* W1    = (const float*)d_in[4];
  const float* U1    = (const float*)d_in[5];
  const float* B1    = (const float*)d_in[6];
  const float* iW1   = (const float*)d_in[7];
  const float* W2    = (const float*)d_in[8];
  const float* U2    = (const float*)d_in[9];
  const float* B2    = (const float*)d_in[10];
  const float* iW2   = (const float*)d_in[11];
  float* out = (float*)d_out;
  float* ws  = (float*)d_ws;

  const long NF = (long)NN*FF;                 // 524288
  ushort* Bph = (ushort*)ws;                   // 4,194,304 ushorts (2,097,152 fl)
  ushort* Bpl = (ushort*)(ws + 2097152);       // 4,194,304 ushorts
  float* h1  = ws + 4194304;                   // 8*NF
  float* sc  = ws + 8388608;                   // 8*4096
  float* pn1 = ws + 8421376;                   // 1024
  float* pn2 = ws + 8422400;                   // 1024
  float* z1  = ws + 8423424;                   // 8*128*128
  float* z2  = ws + 8554496;                   // 8*128*64
  float* Q1  = ws + 8620032;                   // 8*128*128
  float* Q2  = ws + 8751104;                   // 8*128*64
  float* Y   = ws + 8816640;                   // 4096*64
  // total 9,078,784 floats = 36.3 MB of d_ws

  norm_p_k<<<16, 64, 0, stream>>>(p1, p2, pn1, pn2);

  // ---- layer 1 ----
  scores_k<<<dim3(64,8), 256, 0, stream>>>(feats, pn1, sc);
  sortz_k<128><<<8, 1024, 0, stream>>>(sc, feats, z1);
  for (int t = 0; t < TT; ++t)
    cell_k<128><<<32, 128, 0, stream>>>(W1, U1, B1, z1 + (long)t*128*128,
                                        t ? Q1 + (long)(t-1)*128*128 : iW1,
                                        Q1 + (long)t*128*128);
  xmul_pack_k<<<dim3(128,8), 256, 0, stream>>>(feats, Q1, Bph, Bpl);
  gemm_mfma_k<<<512, 256, 0, stream>>>(adj, Bph, Bpl, h1);

  // ---- layer 2 (emb only needed at t=7) ----
  scores_k<<<dim3(64,8), 256, 0, stream>>>(h1, pn2, sc);
  sortz_k<64><<<8, 1024, 0, stream>>>(sc, h1, z2);
  for (int t = 0; t < TT; ++t)
    cell_k<64><<<16, 128, 0, stream>>>(W2, U2, B2, z2 + (long)t*128*64,
                                       t ? Q2 + (long)(t-1)*128*64 : iW2,
                                       Q2 + (long)t*128*64);
  xmul_k64<<<128, 256, 0, stream>>>(h1 + 7*NF, Q2 + (long)7*128*64, Y);
  gemm_adj64_k<<<64, 256, 0, stream>>>(adj + (long)7*NN*NN, Y, out);
}